// Round 9
// baseline (8524.126 us; speedup 1.0000x reference)
//
#include <hip/hip_runtime.h>

#define BB  64
#define TT  256
#define INF 512
#define HH  1024
#define CC  128
#define RING 16

typedef __attribute__((ext_vector_type(8))) short bf16x8;
typedef __attribute__((ext_vector_type(4))) float f32x4;
typedef unsigned long long ull_t;
typedef unsigned short u16;

#define W0_LD 1544   // 1536+8
#define W1_LD 2056   // 2048+8
#define WC_LD 1032   // 1024+8
#define GSC_OFF (16*W0_LD + 16*W1_LD + 16*WC_LD)
#define SMEM_BYTES (GSC_OFF*2 + 2*(4*16*17)*4)   // 156928 B

#define HBUF (BB*HH)                        // elements per h generation
#define WS_HBYTES (2*RING*HBUF*2)           // h0[16] + h1[16] rings bf16 = 4 MiB
#define WS_ZERO_BYTES (WS_HBYTES + 16384)

#define AGENT __HIP_MEMORY_SCOPE_AGENT
#define RLX   __ATOMIC_RELAXED

__device__ __forceinline__ u16 f2bf(float f) {
    union { float f; unsigned u; } v; v.f = f;
    unsigned r = v.u + 0x7fffu + ((v.u >> 16) & 1u);   // RNE
    return (u16)(r >> 16);
}
__device__ __forceinline__ float sigm(float x) { return 1.f / (1.f + __expf(-x)); }

#define MFMA(a,b,c) __builtin_amdgcn_mfma_f32_16x16x32_bf16((a),(b),(c),0,0,0)

// 16B of h via two 8B agent-scope (LLC-direct) loads: no L2 staleness, no inv fence
__device__ __forceinline__ bf16x8 ld_h16(const u16* p) {
    union { ull_t u[2]; bf16x8 v; } x;
    x.u[0] = __hip_atomic_load((const ull_t*)p,       RLX, AGENT);
    x.u[1] = __hip_atomic_load((const ull_t*)(p + 4), RLX, AGENT);
    return x.v;
}

__global__ __launch_bounds__(576, 1)
void lstm_persist(const float* __restrict__ xs,
                  const float* __restrict__ Wih0, const float* __restrict__ Whh0,
                  const float* __restrict__ bih0, const float* __restrict__ bhh0,
                  const float* __restrict__ Wih1, const float* __restrict__ Whh1,
                  const float* __restrict__ bih1, const float* __restrict__ bhh1,
                  const float* __restrict__ Wcls, const float* __restrict__ bcls,
                  float* __restrict__ out,          // f32 [B][C][2T]
                  u16* __restrict__ hws,            // h rings (bf16)
                  unsigned* __restrict__ bar)       // slots0[1024] slots1[1024] slots2[64] flags
{
    extern __shared__ char smem[];
    u16* W0s = (u16*)smem;              // [16][W0_LD]  [W_hh0 | W_ih0]
    u16* W1s = W0s + 16*W0_LD;          // [16][W1_LD]  [W_ih1 | W_hh1]
    u16* WCs = W1s + 16*W1_LD;          // [16][WC_LD]  W_cls slice (blocks 0..31)
    float* gsc0 = (float*)(smem + GSC_OFF*2);       // [4][16][17]
    float* gsc1 = gsc0 + 4*16*17;

    const int blk   = blockIdx.x;       // owns h-cols 4*blk..4*blk+3 (both layers)
    const int tid   = threadIdx.x;
    const int wave  = tid >> 6;         // 0-3: L0 workers, 4-7: L1 workers, 8: aux
    const int lane  = tid & 63;
    const int col16 = lane & 15;
    const int kgrp  = (lane >> 4) << 3;

    u16* ring0 = hws;                   // h0(t) at slot t&15
    u16* ring1 = hws + RING*HBUF;       // h1(t) at slot t&15
    unsigned* slots0 = bar;             // per L0-wave step counters
    unsigned* slots1 = bar + 1024;      // per L1-wave step counters
    unsigned* slots2 = bar + 2048;      // per classifier-wave chunk counters [32]
    const ull_t* myflag = (const ull_t*)(bar + 2560) + (blk & 7)*16;

    // ---- prologue: weights -> LDS (bf16), all 9 waves help
    for (int i = tid; i < 16*1536; i += 576) {
        int r = i / 1536, k = i - r*1536;
        int gr = 4*blk + (r & 3) + HH*(r >> 2);
        float v = (k < HH) ? Whh0[gr*HH + k] : Wih0[gr*INF + (k - HH)];
        W0s[r*W0_LD + k] = f2bf(v);
    }
    for (int i = tid; i < 16*2048; i += 576) {
        int r = i >> 11, k = i & 2047;
        int gr = 4*blk + (r & 3) + HH*(r >> 2);
        float v = (k < HH) ? Wih1[gr*HH + k] : Whh1[gr*HH + (k - HH)];
        W1s[r*W1_LD + k] = f2bf(v);
    }
    if (blk < 32) {
        int cb = (blk & 7) << 4;
        for (int i = tid; i < 16*1024; i += 576) {
            int r = i >> 10, k = i & 1023;
            WCs[r*WC_LD + k] = f2bf(Wcls[(cb + r)*HH + k]);
        }
    }
    __syncthreads();

// poll packed flag: f0 (bits 0-15), f1 (16-31), f2s = 8*chunks (32-63)
#define POLLC(nF0, nF1, nBP) do { \
        const unsigned _n0 = (unsigned)(nF0), _n1 = (unsigned)(nF1), _nb = (unsigned)(nBP); \
        for (;;) { \
            ull_t F_ = __hip_atomic_load(myflag, RLX, AGENT); \
            if ((F_ & 0xffffu) >= _n0 && ((F_ >> 16) & 0xffffu) >= _n1 \
                && (unsigned)(F_ >> 32) >= _nb) break; \
            __builtin_amdgcn_s_sleep(1); \
        } } while (0)

    // ================= aux wave =================
    if (wave == 8) {
        if (blk == 255) {
            // manager: scan slots, publish packed {f0, f1, f2s} to 8 replicated lines
            const ull_t* s0 = (const ull_t*)slots0;
            const ull_t* s1 = (const ull_t*)slots1;
            const ull_t* s2 = (const ull_t*)slots2;
            ull_t* flags = (ull_t*)(bar + 2560);
            unsigned v0 = 0, v1 = 0, v2 = 0;
            while (v0 < TT || v1 < TT || v2 < TT/8) {
                bool ok0 = true, ok1 = true, ok2 = true;
                #pragma unroll
                for (int j = 0; j < 8; ++j) {
                    ull_t a = __hip_atomic_load(s0 + lane*8 + j, RLX, AGENT);
                    ok0 &= ((unsigned)a >= v0 + 1) && ((unsigned)(a >> 32) >= v0 + 1);
                }
                #pragma unroll
                for (int j = 0; j < 8; ++j) {
                    ull_t a = __hip_atomic_load(s1 + lane*8 + j, RLX, AGENT);
                    ok1 &= ((unsigned)a >= v1 + 1) && ((unsigned)(a >> 32) >= v1 + 1);
                }
                if (lane < 16) {
                    ull_t a = __hip_atomic_load(s2 + lane, RLX, AGENT);
                    ok2 = ((unsigned)a >= v2 + 1) && ((unsigned)(a >> 32) >= v2 + 1);
                }
                bool adv = false;
                if (__all(ok0) && v0 < TT)   { ++v0; adv = true; }
                if (__all(ok1) && v1 < TT)   { ++v1; adv = true; }
                if (__all(ok2) && v2 < TT/8) { ++v2; adv = true; }
                if (adv && lane == 0) {
                    ull_t pk = (ull_t)v0 | ((ull_t)v1 << 16) | ((ull_t)(8*v2) << 32);
                    #pragma unroll
                    for (int g = 0; g < 8; ++g)
                        __hip_atomic_store(flags + g*16, pk, RLX, AGENT);
                }
            }
        } else if (blk < 32) {
            // classifier wave: batch rows 16R.., cls cols 16*C8..; processes 8-step chunks
            const int R  = blk >> 3, C8 = blk & 7;
            const int arow2 = (R << 4) + col16;
            const u16*  wcp   = WCs + col16*WC_LD + kgrp;
            const float biasc = bcls[(C8 << 4) + col16];
            for (int c = 0; c < TT/8; ++c) {
                POLLC(0, 8*c + 8, 0);            // f1 >= 8c+8: h0/h1(8c..8c+7) ready
                union { float2 f2[8]; f32x4 f4[4]; } o[4];
                #pragma unroll
                for (int tt = 0; tt < 8; ++tt) {
                    const int t = 8*c + tt;
                    const u16* h0s = ring0 + (unsigned)(t & 15)*HBUF + arow2*HH + kgrp;
                    const u16* h1s = ring1 + (unsigned)(t & 15)*HBUF + arow2*HH + kgrp;
                    f32x4 a0 = { biasc, biasc, biasc, biasc }, a1 = { 0.f, 0.f, 0.f, 0.f };
                    f32x4 b0 = { biasc, biasc, biasc, biasc }, b1 = { 0.f, 0.f, 0.f, 0.f };
                    #pragma unroll 4
                    for (int kc = 0; kc < 32; ++kc) {
                        const bf16x8 w = *(const bf16x8*)(wcp + (kc << 5));
                        const bf16x8 x0 = ld_h16(h0s + (kc << 5));
                        const bf16x8 x1 = ld_h16(h1s + (kc << 5));
                        if (kc & 1) { a1 = MFMA(x0, w, a1); b1 = MFMA(x1, w, b1); }
                        else        { a0 = MFMA(x0, w, a0); b0 = MFMA(x1, w, b0); }
                    }
                    #pragma unroll
                    for (int q = 0; q < 4; ++q)
                        o[q].f2[tt] = make_float2(a0[q] + a1[q], b0[q] + b1[q]);
                }
                const int cc = (C8 << 4) + col16;
                #pragma unroll
                for (int q = 0; q < 4; ++q) {
                    const int br = (R << 4) + ((lane >> 4) << 2) + q;
                    float* po = &out[(ull_t)(br*CC + cc)*(2*TT) + 16*c];
                    #pragma unroll
                    for (int s = 0; s < 4; ++s)
                        __builtin_nontemporal_store(o[q].f4[s], (f32x4*)(po + 4*s));
                }
                asm volatile("s_waitcnt vmcnt(0)" ::: "memory");
                if (lane == 0)
                    __hip_atomic_store(&slots2[blk], (unsigned)(c + 1), RLX, AGENT);
            }
        } else {
            // spinner: keep clocks up until done (low-rate flag check)
            float a = 1.0000001f, b = 0.9999999f;
            for (;;) {
                #pragma unroll 64
                for (int i = 0; i < 2048; ++i) a = __builtin_fmaf(a, b, 1e-7f);
                asm volatile("" :: "v"(a));
                ull_t F = __hip_atomic_load(myflag, RLX, AGENT);
                if (((F >> 16) & 0xffffu) >= (unsigned)TT) break;
            }
        }
        return;
    }

    // ================= worker waves =================
    const int wv   = wave & 3;
    const int gid  = (blk << 2) + wv;
    const int arow = (wv << 4) + col16;
    const int rloc = lane >> 2, jj = lane & 3;
    const u16* w0p = W0s + col16*W0_LD + kgrp;
    const u16* w1p = W1s + col16*W1_LD + kgrp;

    const int grl = 4*blk + (col16 & 3) + HH*(col16 >> 2);

    if (wave < 4) {
        // ---------- L0 worker: the critical chain ----------
        const float bias0 = bih0[grl] + bhh0[grl];
        float c0 = 0.f;
        f32x4 g0A = { bias0, bias0, bias0, bias0 }, g0B = { 0.f, 0.f, 0.f, 0.f };
        {   // prime x-projection for t=0
            const float* xp = xs + (arow*TT + 0)*INF + kgrp;
            #pragma unroll 4
            for (int kc = 0; kc < 16; ++kc) {
                const float4 x0 = *(const float4*)(xp + (kc << 5));
                const float4 x1 = *(const float4*)(xp + (kc << 5) + 4);
                bf16x8 a;
                a[0]=(short)f2bf(x0.x); a[1]=(short)f2bf(x0.y); a[2]=(short)f2bf(x0.z); a[3]=(short)f2bf(x0.w);
                a[4]=(short)f2bf(x1.x); a[5]=(short)f2bf(x1.y); a[6]=(short)f2bf(x1.z); a[7]=(short)f2bf(x1.w);
                const bf16x8 b = *(const bf16x8*)(w0p + ((32 + kc) << 5));
                if (kc & 1) g0B = MFMA(a, b, g0B); else g0A = MFMA(a, b, g0A);
            }
        }
        for (int t = 0; t < TT; ++t) {
            // h0(t-1) visible; ring credit: h0(t-16) consumers (L1 step t-15, cls) done
            POLLC(t, (t >= 16) ? t - 15 : 0, (t >= 16) ? t - 15 : 0);
            const u16* h0p = ring0 + (unsigned)((t + 15) & 15)*HBUF + arow*HH + kgrp;
            #pragma unroll 4
            for (int kc = 0; kc < 32; ++kc) {
                const bf16x8 a = ld_h16(h0p + (kc << 5));
                const bf16x8 b = *(const bf16x8*)(w0p + (kc << 5));
                if (kc & 1) g0B = MFMA(a, b, g0B); else g0A = MFMA(a, b, g0A);
            }
            #pragma unroll
            for (int qq = 0; qq < 4; ++qq)
                gsc0[wv*272 + (((lane >> 4) << 2) + qq)*17 + col16] = g0A[qq] + g0B[qq];
            asm volatile("s_waitcnt lgkmcnt(0)" ::: "memory");
            const float* g = gsc0 + wv*272 + rloc*17;
            const float ig = sigm(g[jj]), fg = sigm(g[4 + jj]);
            const float gt = tanhf(g[8 + jj]), og = sigm(g[12 + jj]);
            c0 = fg*c0 + ig*gt;
            unsigned v = f2bf(og * tanhf(c0));
            unsigned p = v | (__shfl_down(v, 1) << 16);
            ull_t all = ((ull_t)__shfl_down(p, 2) << 32) | (ull_t)p;
            if (jj == 0)
                __hip_atomic_store((ull_t*)(ring0 + (unsigned)(t & 15)*HBUF
                                            + ((wv << 4) + rloc)*HH + (blk << 2)),
                                   all, RLX, AGENT);
            asm volatile("s_waitcnt vmcnt(0)" ::: "memory");
            if (lane == 0)
                __hip_atomic_store(&slots0[gid], (unsigned)(t + 1), RLX, AGENT);
            if (t + 1 < TT) {                            // slack: x-part for t+1
                g0A[0]=bias0; g0A[1]=bias0; g0A[2]=bias0; g0A[3]=bias0;
                g0B[0]=0.f;   g0B[1]=0.f;   g0B[2]=0.f;   g0B[3]=0.f;
                const float* xp = xs + (arow*TT + (t + 1))*INF + kgrp;
                #pragma unroll 4
                for (int kc = 0; kc < 16; ++kc) {
                    const float4 x0 = *(const float4*)(xp + (kc << 5));
                    const float4 x1 = *(const float4*)(xp + (kc << 5) + 4);
                    bf16x8 a;
                    a[0]=(short)f2bf(x0.x); a[1]=(short)f2bf(x0.y); a[2]=(short)f2bf(x0.z); a[3]=(short)f2bf(x0.w);
                    a[4]=(short)f2bf(x1.x); a[5]=(short)f2bf(x1.y); a[6]=(short)f2bf(x1.z); a[7]=(short)f2bf(x1.w);
                    const bf16x8 b = *(const bf16x8*)(w0p + ((32 + kc) << 5));
                    if (kc & 1) g0B = MFMA(a, b, g0B); else g0A = MFMA(a, b, g0A);
                }
            }
        }
    } else {
        // ---------- L1 worker: computes layer-1 step t-1 at loop t ----------
        const float bias1 = bih1[grl] + bhh1[grl];
        float c1 = 0.f;
        for (int t = 1; t <= TT; ++t) {
            // h0(t-1) & h1(t-2) visible; ring credit for h1(t-17) slot reuse
            POLLC(t, t - 1, (t >= 17) ? t - 16 : 0);
            f32x4 g1A = { bias1, bias1, bias1, bias1 }, g1B = { 0.f, 0.f, 0.f, 0.f };
            const u16* h1p = ring1 + (unsigned)((t + 14) & 15)*HBUF + arow*HH + kgrp;
            #pragma unroll 4
            for (int kc = 0; kc < 32; ++kc) {            // h1(t-2) part
                const bf16x8 a = ld_h16(h1p + (kc << 5));
                const bf16x8 b = *(const bf16x8*)(w1p + ((32 + kc) << 5));
                if (kc & 1) g1B = MFMA(a, b, g1B); else g1A = MFMA(a, b, g1A);
            }
            const u16* h0p = ring0 + (unsigned)((t + 15) & 15)*HBUF + arow*HH + kgrp;
            #pragma unroll 4
            for (int kc = 0; kc < 32; ++kc) {            // h0(t-1) part
                const bf16x8 a = ld_h16(h0p + (kc << 5));
                const bf16x8 b = *(const bf16x8*)(w1p + (kc << 5));
                if (kc & 1) g1B = MFMA(a, b, g1B); else g1A = MFMA(a, b, g1A);
            }
            #pragma unroll
            for (int qq = 0; qq < 4; ++qq)
                gsc1[wv*272 + (((lane >> 4) << 2) + qq)*17 + col16] = g1A[qq] + g1B[qq];
            asm volatile("s_waitcnt lgkmcnt(0)" ::: "memory");
            const float* g = gsc1 + wv*272 + rloc*17;
            const float ig = sigm(g[jj]), fg = sigm(g[4 + jj]);
            const float gt = tanhf(g[8 + jj]), og = sigm(g[12 + jj]);
            c1 = fg*c1 + ig*gt;
            unsigned v = f2bf(og * tanhf(c1));
            unsigned p = v | (__shfl_down(v, 1) << 16);
            ull_t all = ((ull_t)__shfl_down(p, 2) << 32) | (ull_t)p;
            if (jj == 0)
                __hip_atomic_store((ull_t*)(ring1 + (unsigned)((t - 1) & 15)*HBUF
                                            + ((wv << 4) + rloc)*HH + (blk << 2)),
                                   all, RLX, AGENT);
            asm volatile("s_waitcnt vmcnt(0)" ::: "memory");
            if (lane == 0)
                __hip_atomic_store(&slots1[gid], (unsigned)t, RLX, AGENT);
        }
    }
}

extern "C" void kernel_launch(void* const* d_in, const int* in_sizes, int n_in,
                              void* d_out, int out_size, void* d_ws, size_t ws_size,
                              hipStream_t stream) {
    const float* xs   = (const float*)d_in[0];
    const float* Wih0 = (const float*)d_in[1];
    const float* Whh0 = (const float*)d_in[2];
    const float* bih0 = (const float*)d_in[3];
    const float* bhh0 = (const float*)d_in[4];
    const float* Wih1 = (const float*)d_in[5];
    const float* Whh1 = (const float*)d_in[6];
    const float* bih1 = (const float*)d_in[7];
    const float* bhh1 = (const float*)d_in[8];
    const float* Wcls = (const float*)d_in[9];
    const float* bcls = (const float*)d_in[10];
    float* out = (float*)d_out;
    u16*      hws = (u16*)d_ws;
    unsigned* bar = (unsigned*)((char*)d_ws + WS_HBYTES);

    (void)hipMemsetAsync(d_ws, 0, WS_ZERO_BYTES, stream);

    (void)hipFuncSetAttribute((const void*)lstm_persist,
                              hipFuncAttributeMaxDynamicSharedMemorySize, SMEM_BYTES);

    lstm_persist<<<dim3(256), dim3(576), SMEM_BYTES, stream>>>(
        xs, Wih0, Whh0, bih0, bhh0, Wih1, Whh1, bih1, bhh1, Wcls, bcls,
        out, hws, bar);
}

// Round 10
// 6207.734 us; speedup vs baseline: 1.3731x; 1.3731x over previous
//
#include <hip/hip_runtime.h>

#define BB  64
#define TT  256
#define INF 512
#define HH  1024
#define CC  128

typedef __attribute__((ext_vector_type(8))) short bf16x8;
typedef __attribute__((ext_vector_type(4))) float f32x4;
typedef unsigned long long ull_t;
typedef unsigned short u16;

#define W0_LD 1544   // 1536+8
#define W1_LD 2056   // 2048+8
#define WC_LD 1032   // 1024+8
#define GSC_OFF (16*W0_LD + 16*W1_LD + 16*WC_LD)
#define SMEM_BYTES (GSC_OFF*2 + 2*(4*16*17)*4)   // 156928 B

#define HBUF (BB*HH)                 // elements per h generation (128 KB)
#define BAR_BYTES 65536

#define AGENT __HIP_MEMORY_SCOPE_AGENT
#define RLX   __ATOMIC_RELAXED

__device__ __forceinline__ u16 f2bf(float f) {
    union { float f; unsigned u; } v; v.f = f;
    unsigned r = v.u + 0x7fffu + ((v.u >> 16) & 1u);   // RNE
    return (u16)(r >> 16);
}
__device__ __forceinline__ float sigm(float x) { return 1.f / (1.f + __expf(-x)); }

#define MFMA(a,b,c) __builtin_amdgcn_mfma_f32_16x16x32_bf16((a),(b),(c),0,0,0)

template<bool PLAIN>
__device__ __forceinline__ bf16x8 ld16(const u16* p) {
    if constexpr (PLAIN) {
        return *(const bf16x8*)p;   // L2-cacheable: safe, address written once before flag
    } else {
        union { ull_t u[2]; bf16x8 v; } x;
        x.u[0] = __hip_atomic_load((const ull_t*)p,       RLX, AGENT);
        x.u[1] = __hip_atomic_load((const ull_t*)(p + 4), RLX, AGENT);
        return x.v;
    }
}

// busy poll: FMA chain keeps SIMD (and DPM clocks) active; ~430ns granularity
#define POLLC(nF0, nF1, nBP) do { \
        const unsigned _n0 = (unsigned)(nF0), _n1 = (unsigned)(nF1), _nb = (unsigned)(nBP); \
        float _z = 1.f; \
        for (;;) { \
            ull_t F_ = __hip_atomic_load(myflag, RLX, AGENT); \
            if ((F_ & 0xffffu) >= _n0 && ((F_ >> 16) & 0xffffu) >= _n1 \
                && (unsigned)(F_ >> 32) >= _nb) break; \
            _Pragma("unroll 16") \
            for (int _i = 0; _i < 256; ++_i) _z = __builtin_fmaf(_z, 0.99999988f, 1e-9f); \
            asm volatile("" :: "v"(_z)); \
        } \
        asm volatile("" ::: "memory"); \
    } while (0)

template<int DEPTH, bool PLAIN>
__global__ __launch_bounds__(576, 1)
void lstm_persist(const float* __restrict__ xs,
                  const float* __restrict__ Wih0, const float* __restrict__ Whh0,
                  const float* __restrict__ bih0, const float* __restrict__ bhh0,
                  const float* __restrict__ Wih1, const float* __restrict__ Whh1,
                  const float* __restrict__ bih1, const float* __restrict__ bhh1,
                  const float* __restrict__ Wcls, const float* __restrict__ bcls,
                  float* __restrict__ out,          // f32 [B][C][2T]
                  u16* __restrict__ hws,            // h slot arrays
                  unsigned* __restrict__ bar)       // slots0[1024] slots1[1024] slots2[32] flags[64]
{
    extern __shared__ char smem[];
    u16* W0s = (u16*)smem;              // [16][W0_LD]  [W_hh0 | W_ih0]
    u16* W1s = W0s + 16*W0_LD;          // [16][W1_LD]  [W_ih1 | W_hh1]
    u16* WCs = W1s + 16*W1_LD;          // [16][WC_LD]  W_cls slice (blocks 0..31)
    float* gsc0 = (float*)(smem + GSC_OFF*2);       // [4][16][17]
    float* gsc1 = gsc0 + 4*16*17;

    const int blk   = blockIdx.x;       // owns h-cols 4*blk..4*blk+3 (both layers)
    const int tid   = threadIdx.x;
    const int wave  = tid >> 6;         // 0-3: L0, 4-7: L1, 8: aux
    const int lane  = tid & 63;
    const int col16 = lane & 15;
    const int kgrp  = (lane >> 4) << 3;

    u16* ring0 = hws;                           // h0 value x at slot (x+2)%DEPTH
    u16* ring1 = hws + (size_t)DEPTH*HBUF;      // h1 value x at slot (x+2)%DEPTH
    unsigned* slots0 = bar;
    unsigned* slots1 = bar + 1024;
    unsigned* slots2 = bar + 2048;              // [32] cls chunk counters
    ull_t*    flags  = (ull_t*)(bar + 2560);    // 64 replicated lines, stride 16 ull
    const ull_t* myflag = flags + (blk & 63)*16;

#define SLOT(x) ((unsigned)(((x) + 2) % DEPTH))

    // ---- prologue: weights -> LDS (bf16)
    for (int i = tid; i < 16*1536; i += 576) {
        int r = i / 1536, k = i - r*1536;
        int gr = 4*blk + (r & 3) + HH*(r >> 2);
        float v = (k < HH) ? Whh0[gr*HH + k] : Wih0[gr*INF + (k - HH)];
        W0s[r*W0_LD + k] = f2bf(v);
    }
    for (int i = tid; i < 16*2048; i += 576) {
        int r = i >> 11, k = i & 2047;
        int gr = 4*blk + (r & 3) + HH*(r >> 2);
        float v = (k < HH) ? Wih1[gr*HH + k] : Whh1[gr*HH + (k - HH)];
        W1s[r*W1_LD + k] = f2bf(v);
    }
    if (blk < 32) {
        int cb = (blk & 7) << 4;
        for (int i = tid; i < 16*1024; i += 576) {
            int r = i >> 10, k = i & 1023;
            WCs[r*WC_LD + k] = f2bf(Wcls[(cb + r)*HH + k]);
        }
    }
    __syncthreads();

    // ================= aux wave =================
    if (wave == 8) {
        if (blk == 255) {
            // manager: scan per-wave slots, publish packed {f0,f1,f2s} to 64 lines
            const ull_t* s0 = (const ull_t*)slots0;
            const ull_t* s1 = (const ull_t*)slots1;
            const ull_t* s2 = (const ull_t*)slots2;
            unsigned v0 = 0, v1 = 0, v2 = 0;
            while (v0 < TT || v1 < TT || v2 < TT/8) {
                bool ok0 = true, ok1 = true, ok2 = true;
                #pragma unroll
                for (int j = 0; j < 8; ++j) {
                    ull_t a = __hip_atomic_load(s0 + lane*8 + j, RLX, AGENT);
                    ok0 &= ((unsigned)a >= v0 + 1) && ((unsigned)(a >> 32) >= v0 + 1);
                }
                #pragma unroll
                for (int j = 0; j < 8; ++j) {
                    ull_t a = __hip_atomic_load(s1 + lane*8 + j, RLX, AGENT);
                    ok1 &= ((unsigned)a >= v1 + 1) && ((unsigned)(a >> 32) >= v1 + 1);
                }
                if (lane < 16) {
                    ull_t a = __hip_atomic_load(s2 + lane, RLX, AGENT);
                    ok2 = ((unsigned)a >= v2 + 1) && ((unsigned)(a >> 32) >= v2 + 1);
                }
                bool adv = false;
                if (__all(ok0) && v0 < TT)   { ++v0; adv = true; }
                if (__all(ok1) && v1 < TT)   { ++v1; adv = true; }
                if (__all(ok2) && v2 < TT/8) { ++v2; adv = true; }
                if (adv) {
                    ull_t pk = (ull_t)v0 | ((ull_t)v1 << 16) | ((ull_t)(8*v2) << 32);
                    __hip_atomic_store(flags + lane*16, pk, RLX, AGENT);  // all 64 lines at once
                }
            }
        } else if (blk < 32) {
            // classifier wave: batch rows 16R.., cls cols 16*C8..; 8-step chunks
            const int R  = blk >> 3, C8 = blk & 7;
            const int arow2 = (R << 4) + col16;
            const u16*  wcp   = WCs + col16*WC_LD + kgrp;
            const float biasc = bcls[(C8 << 4) + col16];
            for (int c = 0; c < TT/8; ++c) {
                POLLC(0, 8*c + 8, 0);            // f1 >= 8c+8: h0/h1(8c..8c+7) final
                union { float2 f2[8]; f32x4 f4[4]; } o[4];
                #pragma unroll
                for (int tt = 0; tt < 8; ++tt) {
                    const int t = 8*c + tt;
                    const u16* h0s = ring0 + (size_t)SLOT(t)*HBUF + arow2*HH + kgrp;
                    const u16* h1s = ring1 + (size_t)SLOT(t)*HBUF + arow2*HH + kgrp;
                    f32x4 a0 = { biasc, biasc, biasc, biasc }, a1 = { 0.f, 0.f, 0.f, 0.f };
                    f32x4 b0 = { biasc, biasc, biasc, biasc }, b1 = { 0.f, 0.f, 0.f, 0.f };
                    #pragma unroll 4
                    for (int kc = 0; kc < 32; ++kc) {
                        const bf16x8 w  = *(const bf16x8*)(wcp + (kc << 5));
                        const bf16x8 x0 = ld16<PLAIN>(h0s + (kc << 5));
                        const bf16x8 x1 = ld16<PLAIN>(h1s + (kc << 5));
                        if (kc & 1) { a1 = MFMA(x0, w, a1); b1 = MFMA(x1, w, b1); }
                        else        { a0 = MFMA(x0, w, a0); b0 = MFMA(x1, w, b0); }
                    }
                    #pragma unroll
                    for (int q = 0; q < 4; ++q)
                        o[q].f2[tt] = make_float2(a0[q] + a1[q], b0[q] + b1[q]);
                }
                const int cc = (C8 << 4) + col16;
                #pragma unroll
                for (int q = 0; q < 4; ++q) {
                    const int br = (R << 4) + ((lane >> 4) << 2) + q;
                    float* po = &out[(ull_t)(br*CC + cc)*(2*TT) + 16*c];
                    #pragma unroll
                    for (int s = 0; s < 4; ++s)
                        __builtin_nontemporal_store(o[q].f4[s], (f32x4*)(po + 4*s));
                }
                asm volatile("s_waitcnt vmcnt(0)" ::: "memory");
                if (lane == 0)
                    __hip_atomic_store(&slots2[blk], (unsigned)(c + 1), RLX, AGENT);
            }
        }
        return;   // other aux waves exit (busy-poll keeps clocks up now)
    }

    // ================= worker waves =================
    const int wv   = wave & 3;
    const int gid  = (blk << 2) + wv;
    const int arow = (wv << 4) + col16;
    const int rloc = lane >> 2, jj = lane & 3;
    const u16* w0p = W0s + col16*W0_LD + kgrp;
    const u16* w1p = W1s + col16*W1_LD + kgrp;
    const int  grl = 4*blk + (col16 & 3) + HH*(col16 >> 2);

    if (wave < 4) {
        // ---------- L0 worker ----------
        const float bias0 = bih0[grl] + bhh0[grl];
        float c0 = 0.f;
        f32x4 g0A = { bias0, bias0, bias0, bias0 }, g0B = { 0.f, 0.f, 0.f, 0.f };
        {   // prime x-projection for t=0
            const float* xp = xs + (arow*TT + 0)*INF + kgrp;
            #pragma unroll 4
            for (int kc = 0; kc < 16; ++kc) {
                const float4 x0 = *(const float4*)(xp + (kc << 5));
                const float4 x1 = *(const float4*)(xp + (kc << 5) + 4);
                bf16x8 a;
                a[0]=(short)f2bf(x0.x); a[1]=(short)f2bf(x0.y); a[2]=(short)f2bf(x0.z); a[3]=(short)f2bf(x0.w);
                a[4]=(short)f2bf(x1.x); a[5]=(short)f2bf(x1.y); a[6]=(short)f2bf(x1.z); a[7]=(short)f2bf(x1.w);
                const bf16x8 b = *(const bf16x8*)(w0p + ((32 + kc) << 5));
                if (kc & 1) g0B = MFMA(a, b, g0B); else g0A = MFMA(a, b, g0A);
            }
        }
        for (int t = 0; t < TT; ++t) {
            // write-credit only matters when slots are reused (DEPTH <= TT)
            const unsigned cr = (DEPTH <= TT && t >= DEPTH - 1) ? (unsigned)(t - DEPTH + 1) : 0u;
            POLLC(t, cr, cr);
            const u16* h0p = ring0 + (size_t)SLOT(t - 1)*HBUF + arow*HH + kgrp;
            #pragma unroll 4
            for (int kc = 0; kc < 32; ++kc) {
                const bf16x8 a = ld16<PLAIN>(h0p + (kc << 5));
                const bf16x8 b = *(const bf16x8*)(w0p + (kc << 5));
                if (kc & 1) g0B = MFMA(a, b, g0B); else g0A = MFMA(a, b, g0A);
            }
            #pragma unroll
            for (int qq = 0; qq < 4; ++qq)
                gsc0[wv*272 + (((lane >> 4) << 2) + qq)*17 + col16] = g0A[qq] + g0B[qq];
            asm volatile("s_waitcnt lgkmcnt(0)" ::: "memory");
            const float* g = gsc0 + wv*272 + rloc*17;
            const float ig = sigm(g[jj]), fg = sigm(g[4 + jj]);
            const float gt = tanhf(g[8 + jj]), og = sigm(g[12 + jj]);
            c0 = fg*c0 + ig*gt;
            unsigned v = f2bf(og * tanhf(c0));
            unsigned p = v | (__shfl_down(v, 1) << 16);
            ull_t all = ((ull_t)__shfl_down(p, 2) << 32) | (ull_t)p;
            if (jj == 0)
                __hip_atomic_store((ull_t*)(ring0 + (size_t)SLOT(t)*HBUF
                                            + ((wv << 4) + rloc)*HH + (blk << 2)),
                                   all, RLX, AGENT);
            asm volatile("s_waitcnt vmcnt(0)" ::: "memory");
            if (lane == 0)
                __hip_atomic_store(&slots0[gid], (unsigned)(t + 1), RLX, AGENT);
            if (t + 1 < TT) {                            // slack: x-part for t+1
                g0A[0]=bias0; g0A[1]=bias0; g0A[2]=bias0; g0A[3]=bias0;
                g0B[0]=0.f;   g0B[1]=0.f;   g0B[2]=0.f;   g0B[3]=0.f;
                const float* xp = xs + (arow*TT + (t + 1))*INF + kgrp;
                #pragma unroll 4
                for (int kc = 0; kc < 16; ++kc) {
                    const float4 x0 = *(const float4*)(xp + (kc << 5));
                    const float4 x1 = *(const float4*)(xp + (kc << 5) + 4);
                    bf16x8 a;
                    a[0]=(short)f2bf(x0.x); a[1]=(short)f2bf(x0.y); a[2]=(short)f2bf(x0.z); a[3]=(short)f2bf(x0.w);
                    a[4]=(short)f2bf(x1.x); a[5]=(short)f2bf(x1.y); a[6]=(short)f2bf(x1.z); a[7]=(short)f2bf(x1.w);
                    const bf16x8 b = *(const bf16x8*)(w0p + ((32 + kc) << 5));
                    if (kc & 1) g0B = MFMA(a, b, g0B); else g0A = MFMA(a, b, g0A);
                }
            }
        }
    } else {
        // ---------- L1 worker: layer-1 step t-1 at loop t ----------
        const float bias1 = bih1[grl] + bhh1[grl];
        float c1 = 0.f;
        for (int t = 1; t <= TT; ++t) {
            // phase 1: h1(t-2) part — gated only on older f1 (fills L0's wait window)
            const unsigned crb = (DEPTH <= TT && t >= DEPTH) ? (unsigned)(t - DEPTH) : 0u;
            POLLC(0, t - 1, crb);
            f32x4 g1A = { bias1, bias1, bias1, bias1 }, g1B = { 0.f, 0.f, 0.f, 0.f };
            const u16* h1p = ring1 + (size_t)SLOT(t - 2)*HBUF + arow*HH + kgrp;
            #pragma unroll 4
            for (int kc = 0; kc < 32; ++kc) {
                const bf16x8 a = ld16<PLAIN>(h1p + (kc << 5));
                const bf16x8 b = *(const bf16x8*)(w1p + ((32 + kc) << 5));
                if (kc & 1) g1B = MFMA(a, b, g1B); else g1A = MFMA(a, b, g1A);
            }
            // phase 2: h0(t-1) part
            POLLC(t, 0, 0);
            const u16* h0p = ring0 + (size_t)SLOT(t - 1)*HBUF + arow*HH + kgrp;
            #pragma unroll 4
            for (int kc = 0; kc < 32; ++kc) {
                const bf16x8 a = ld16<PLAIN>(h0p + (kc << 5));
                const bf16x8 b = *(const bf16x8*)(w1p + (kc << 5));
                if (kc & 1) g1B = MFMA(a, b, g1B); else g1A = MFMA(a, b, g1A);
            }
            #pragma unroll
            for (int qq = 0; qq < 4; ++qq)
                gsc1[wv*272 + (((lane >> 4) << 2) + qq)*17 + col16] = g1A[qq] + g1B[qq];
            asm volatile("s_waitcnt lgkmcnt(0)" ::: "memory");
            const float* g = gsc1 + wv*272 + rloc*17;
            const float ig = sigm(g[jj]), fg = sigm(g[4 + jj]);
            const float gt = tanhf(g[8 + jj]), og = sigm(g[12 + jj]);
            c1 = fg*c1 + ig*gt;
            unsigned v = f2bf(og * tanhf(c1));
            unsigned p = v | (__shfl_down(v, 1) << 16);
            ull_t all = ((ull_t)__shfl_down(p, 2) << 32) | (ull_t)p;
            if (jj == 0)
                __hip_atomic_store((ull_t*)(ring1 + (size_t)SLOT(t - 1)*HBUF
                                            + ((wv << 4) + rloc)*HH + (blk << 2)),
                                   all, RLX, AGENT);
            asm volatile("s_waitcnt vmcnt(0)" ::: "memory");
            if (lane == 0)
                __hip_atomic_store(&slots1[gid], (unsigned)t, RLX, AGENT);
        }
    }
#undef SLOT
}

template<int DEPTH, bool PLAIN>
static void launch_tier(const float* xs, const float* Wih0, const float* Whh0,
                        const float* bih0, const float* bhh0,
                        const float* Wih1, const float* Whh1,
                        const float* bih1, const float* bhh1,
                        const float* Wcls, const float* bcls,
                        float* out, void* d_ws, hipStream_t stream) {
    u16* hws = (u16*)d_ws;
    size_t ringB = (size_t)DEPTH*HBUF*2;
    unsigned* bar = (unsigned*)((char*)d_ws + 2*ringB);
    // zero: slots 0-1 of both rings (h(-1)/h(-2) = 0) + barrier region
    (void)hipMemsetAsync(hws, 0, 2*(size_t)HBUF*2, stream);
    (void)hipMemsetAsync((char*)hws + ringB, 0, 2*(size_t)HBUF*2, stream);
    (void)hipMemsetAsync(bar, 0, BAR_BYTES, stream);
    (void)hipFuncSetAttribute((const void*)lstm_persist<DEPTH, PLAIN>,
                              hipFuncAttributeMaxDynamicSharedMemorySize, SMEM_BYTES);
    lstm_persist<DEPTH, PLAIN><<<dim3(256), dim3(576), SMEM_BYTES, stream>>>(
        xs, Wih0, Whh0, bih0, bhh0, Wih1, Whh1, bih1, bhh1, Wcls, bcls,
        out, hws, bar);
}

extern "C" void kernel_launch(void* const* d_in, const int* in_sizes, int n_in,
                              void* d_out, int out_size, void* d_ws, size_t ws_size,
                              hipStream_t stream) {
    const float* xs   = (const float*)d_in[0];
    const float* Wih0 = (const float*)d_in[1];
    const float* Whh0 = (const float*)d_in[2];
    const float* bih0 = (const float*)d_in[3];
    const float* bhh0 = (const float*)d_in[4];
    const float* Wih1 = (const float*)d_in[5];
    const float* Whh1 = (const float*)d_in[6];
    const float* bih1 = (const float*)d_in[7];
    const float* bhh1 = (const float*)d_in[8];
    const float* Wcls = (const float*)d_in[9];
    const float* bcls = (const float*)d_in[10];
    float* out = (float*)d_out;

    auto need = [](int depth) { return (size_t)2*depth*HBUF*2 + BAR_BYTES; };

    if (ws_size >= need(258))       // never-reused slots: plain cached loads, no fences
        launch_tier<258, true >(xs,Wih0,Whh0,bih0,bhh0,Wih1,Whh1,bih1,bhh1,Wcls,bcls,out,d_ws,stream);
    else if (ws_size >= need(32))
        launch_tier< 32, false>(xs,Wih0,Whh0,bih0,bhh0,Wih1,Whh1,bih1,bhh1,Wcls,bcls,out,d_ws,stream);
    else if (ws_size >= need(16))
        launch_tier< 16, false>(xs,Wih0,Whh0,bih0,bhh0,Wih1,Whh1,bih1,bhh1,Wcls,bcls,out,d_ws,stream);
    else
        launch_tier<  8, false>(xs,Wih0,Whh0,bih0,bhh0,Wih1,Whh1,bih1,bhh1,Wcls,bcls,out,d_ws,stream);
}

// Round 11
// 5395.748 us; speedup vs baseline: 1.5798x; 1.1505x over previous
//
#include <hip/hip_runtime.h>

#define BB  64
#define TT  256
#define INF 512
#define HH  1024
#define CC  128

typedef __attribute__((ext_vector_type(8))) short bf16x8;
typedef __attribute__((ext_vector_type(4))) float f32x4;
typedef unsigned long long ull_t;
typedef unsigned short u16;

#define W0_LD 1544   // 1536+8
#define W1_LD 2056   // 2048+8
#define WC_LD 1032   // 1024+8
#define GSC_OFF (16*W0_LD + 16*W1_LD + 16*WC_LD)
#define SMEM_BYTES (GSC_OFF*2 + 2*(4*16*17)*4 + 64)   // + sync counters

#define HBUF (BB*HH)                 // elements per h generation (128 KB)
#define BAR_BYTES 65536

#define AGENT __HIP_MEMORY_SCOPE_AGENT
#define RLX   __ATOMIC_RELAXED

__device__ __forceinline__ u16 f2bf(float f) {
    union { float f; unsigned u; } v; v.f = f;
    unsigned r = v.u + 0x7fffu + ((v.u >> 16) & 1u);   // RNE
    return (u16)(r >> 16);
}
__device__ __forceinline__ float sigm(float x) { return 1.f / (1.f + __expf(-x)); }

#define MFMA(a,b,c) __builtin_amdgcn_mfma_f32_16x16x32_bf16((a),(b),(c),0,0,0)

template<bool PLAIN>
__device__ __forceinline__ bf16x8 ld16(const u16* p) {
    if constexpr (PLAIN) {
        return *(const bf16x8*)p;   // address written exactly once before its flag -> no staleness
    } else {
        union { ull_t u[2]; bf16x8 v; } x;
        x.u[0] = __hip_atomic_load((const ull_t*)p,       RLX, AGENT);
        x.u[1] = __hip_atomic_load((const ull_t*)(p + 4), RLX, AGENT);
        return x.v;
    }
}

// direct poll over per-block flags: one pass = 1-2 x 16B/lane from this block's replica
#define POLL3(nF0, nF1, nFC) do { \
        const unsigned _n0 = (unsigned)(nF0), _n1 = (unsigned)(nF1), _nc = (unsigned)(nFC); \
        float _z = 1.f; \
        for (;;) { \
            bool _ok = true; \
            if (_n0) { \
                ull_t _a = __hip_atomic_load(f0p + (lane << 1),     RLX, AGENT); \
                ull_t _b = __hip_atomic_load(f0p + (lane << 1) + 1, RLX, AGENT); \
                _ok &= ((unsigned)_a >= _n0) && ((unsigned)(_a >> 32) >= _n0) \
                    && ((unsigned)_b >= _n0) && ((unsigned)(_b >> 32) >= _n0); \
            } \
            if (_n1) { \
                ull_t _a = __hip_atomic_load(f1p + (lane << 1),     RLX, AGENT); \
                ull_t _b = __hip_atomic_load(f1p + (lane << 1) + 1, RLX, AGENT); \
                _ok &= ((unsigned)_a >= _n1) && ((unsigned)(_a >> 32) >= _n1) \
                    && ((unsigned)_b >= _n1) && ((unsigned)(_b >> 32) >= _n1); \
            } \
            if (_nc && lane < 16) { \
                ull_t _a = __hip_atomic_load(fcp + lane, RLX, AGENT); \
                _ok &= ((unsigned)_a >= _nc) && ((unsigned)(_a >> 32) >= _nc); \
            } \
            if (__all(_ok)) break; \
            _Pragma("unroll 16") \
            for (int _i = 0; _i < 256; ++_i) _z = __builtin_fmaf(_z, 0.99999988f, 1e-9f); \
            asm volatile("" :: "v"(_z)); \
        } \
        asm volatile("" ::: "memory"); \
    } while (0)

// per-wave arrive: LDS counter agg across 4 waves; last arriver publishes 8 replicas
#define ARRIVE(cntp, target, base256, val) do { \
        unsigned _old = 0; \
        if (lane == 0) _old = atomicAdd((cntp), 1u); \
        _old = (unsigned)__shfl((int)_old, 0); \
        if (_old == (unsigned)(target) && lane < 8) \
            __hip_atomic_store(&bar[(base256) + lane*256 + blk], (unsigned)(val), RLX, AGENT); \
    } while (0)

template<int DEPTH, bool PLAIN>
__global__ __launch_bounds__(576, 1)
void lstm_persist(const float* __restrict__ xs,
                  const float* __restrict__ Wih0, const float* __restrict__ Whh0,
                  const float* __restrict__ bih0, const float* __restrict__ bhh0,
                  const float* __restrict__ Wih1, const float* __restrict__ Whh1,
                  const float* __restrict__ bih1, const float* __restrict__ bhh1,
                  const float* __restrict__ Wcls, const float* __restrict__ bcls,
                  float* __restrict__ out,          // f32 [B][C][2T]
                  u16* __restrict__ hws,            // h slot arrays
                  unsigned* __restrict__ bar)       // flag0[8][256] flag1[8][256] flagC[8][64]
{
    extern __shared__ char smem[];
    u16* W0s = (u16*)smem;              // [16][W0_LD]  [W_hh0 | W_ih0]
    u16* W1s = W0s + 16*W0_LD;          // [16][W1_LD]  [W_ih1 | W_hh1]
    u16* WCs = W1s + 16*W1_LD;          // [16][WC_LD]  W_cls slice (blocks 0..31)
    float* gsc0 = (float*)(smem + GSC_OFF*2);       // [4][16][17]
    float* gsc1 = gsc0 + 4*16*17;
    unsigned* scnt = (unsigned*)(gsc1 + 4*16*17);   // [0]=L0 arrivals, [1]=L1 arrivals

    const int blk   = blockIdx.x;       // owns h-cols 4*blk..4*blk+3 (both layers)
    const int tid   = threadIdx.x;
    const int wave  = tid >> 6;         // 0-3: L0, 4-7: L1, 8: cls/exit
    const int lane  = tid & 63;
    const int col16 = lane & 15;
    const int kgrp  = (lane >> 4) << 3;

    u16* ring0 = hws;                           // h0 value x at slot (x+2)%DEPTH
    u16* ring1 = hws + (size_t)DEPTH*HBUF;
    const ull_t* f0p = (const ull_t*)(bar + (blk & 7)*256);
    const ull_t* f1p = (const ull_t*)(bar + 2048 + (blk & 7)*256);
    const ull_t* fcp = (const ull_t*)(bar + 4096 + (blk & 7)*64);

#define SLOT(x) ((unsigned)(((x) + 2) % DEPTH))

    // ---- prologue: weights -> LDS (bf16)
    if (tid < 2) scnt[tid] = 0;
    for (int i = tid; i < 16*1536; i += 576) {
        int r = i / 1536, k = i - r*1536;
        int gr = 4*blk + (r & 3) + HH*(r >> 2);
        float v = (k < HH) ? Whh0[gr*HH + k] : Wih0[gr*INF + (k - HH)];
        W0s[r*W0_LD + k] = f2bf(v);
    }
    for (int i = tid; i < 16*2048; i += 576) {
        int r = i >> 11, k = i & 2047;
        int gr = 4*blk + (r & 3) + HH*(r >> 2);
        float v = (k < HH) ? Wih1[gr*HH + k] : Whh1[gr*HH + (k - HH)];
        W1s[r*W1_LD + k] = f2bf(v);
    }
    if (blk < 32) {
        int cb = (blk & 7) << 4;
        for (int i = tid; i < 16*1024; i += 576) {
            int r = i >> 10, k = i & 1023;
            WCs[r*WC_LD + k] = f2bf(Wcls[(cb + r)*HH + k]);
        }
    }
    __syncthreads();

    // ================= aux wave (cls for blk<32, else exit) =================
    if (wave == 8) {
        if (blk < 32) {
            const int R  = blk >> 3, C8 = blk & 7;
            const int arow2 = (R << 4) + col16;
            const u16*  wcp   = WCs + col16*WC_LD + kgrp;
            const float biasc = bcls[(C8 << 4) + col16];
            for (int c = 0; c < TT/8; ++c) {
                POLL3(0, 8*c + 8, 0);            // h0/h1(8c..8c+7) final everywhere
                union { float2 f2[8]; f32x4 f4[4]; } o[4];
                #pragma unroll
                for (int tt = 0; tt < 8; ++tt) {
                    const int t = 8*c + tt;
                    const u16* h0s = ring0 + (size_t)SLOT(t)*HBUF + arow2*HH + kgrp;
                    const u16* h1s = ring1 + (size_t)SLOT(t)*HBUF + arow2*HH + kgrp;
                    f32x4 a0 = { biasc, biasc, biasc, biasc }, a1 = { 0.f, 0.f, 0.f, 0.f };
                    f32x4 b0 = { biasc, biasc, biasc, biasc }, b1 = { 0.f, 0.f, 0.f, 0.f };
                    #pragma unroll 4
                    for (int kc = 0; kc < 32; ++kc) {
                        const bf16x8 w  = *(const bf16x8*)(wcp + (kc << 5));
                        const bf16x8 x0 = ld16<PLAIN>(h0s + (kc << 5));
                        const bf16x8 x1 = ld16<PLAIN>(h1s + (kc << 5));
                        if (kc & 1) { a1 = MFMA(x0, w, a1); b1 = MFMA(x1, w, b1); }
                        else        { a0 = MFMA(x0, w, a0); b0 = MFMA(x1, w, b0); }
                    }
                    #pragma unroll
                    for (int q = 0; q < 4; ++q)
                        o[q].f2[tt] = make_float2(a0[q] + a1[q], b0[q] + b1[q]);
                }
                const int cc = (C8 << 4) + col16;
                #pragma unroll
                for (int q = 0; q < 4; ++q) {
                    const int br = (R << 4) + ((lane >> 4) << 2) + q;
                    float* po = &out[(ull_t)(br*CC + cc)*(2*TT) + 16*c];
                    #pragma unroll
                    for (int s = 0; s < 4; ++s)
                        __builtin_nontemporal_store(o[q].f4[s], (f32x4*)(po + 4*s));
                }
                asm volatile("s_waitcnt vmcnt(0)" ::: "memory");
                if (lane < 8)
                    __hip_atomic_store(&bar[4096 + lane*64 + blk], (unsigned)(c + 1), RLX, AGENT);
            }
        }
        return;
    }

    // ================= worker waves =================
    const int wv   = wave & 3;
    const int arow = (wv << 4) + col16;
    const int rloc = lane >> 2, jj = lane & 3;
    const u16* w0p = W0s + col16*W0_LD + kgrp;
    const u16* w1p = W1s + col16*W1_LD + kgrp;
    const int  grl = 4*blk + (col16 & 3) + HH*(col16 >> 2);

    if (wave < 4) {
        // ---------- L0 worker: the critical chain ----------
        const float bias0 = bih0[grl] + bhh0[grl];
        float c0 = 0.f;
        f32x4 g0A = { bias0, bias0, bias0, bias0 }, g0B = { 0.f, 0.f, 0.f, 0.f };
        {   // prime x-projection for t=0
            const float* xp = xs + (arow*TT + 0)*INF + kgrp;
            #pragma unroll 4
            for (int kc = 0; kc < 16; ++kc) {
                const float4 x0 = *(const float4*)(xp + (kc << 5));
                const float4 x1 = *(const float4*)(xp + (kc << 5) + 4);
                bf16x8 a;
                a[0]=(short)f2bf(x0.x); a[1]=(short)f2bf(x0.y); a[2]=(short)f2bf(x0.z); a[3]=(short)f2bf(x0.w);
                a[4]=(short)f2bf(x1.x); a[5]=(short)f2bf(x1.y); a[6]=(short)f2bf(x1.z); a[7]=(short)f2bf(x1.w);
                const bf16x8 b = *(const bf16x8*)(w0p + ((32 + kc) << 5));
                if (kc & 1) g0B = MFMA(a, b, g0B); else g0A = MFMA(a, b, g0A);
            }
        }
        for (int t = 0; t < TT; ++t) {
            unsigned n1c = 0, ncc = 0;
            if constexpr (DEPTH <= TT) {            // slot-reuse credits
                if (t >= DEPTH) { n1c = (unsigned)(t - DEPTH + 1);
                                  ncc = (unsigned)((t - DEPTH)/8 + 1); }
            }
            POLL3(t, n1c, ncc);                     // h0(t-1) visible everywhere
            const u16* h0p = ring0 + (size_t)SLOT(t - 1)*HBUF + arow*HH + kgrp;
            #pragma unroll 4
            for (int kc = 0; kc < 32; ++kc) {
                const bf16x8 a = ld16<PLAIN>(h0p + (kc << 5));
                const bf16x8 b = *(const bf16x8*)(w0p + (kc << 5));
                if (kc & 1) g0B = MFMA(a, b, g0B); else g0A = MFMA(a, b, g0A);
            }
            #pragma unroll
            for (int qq = 0; qq < 4; ++qq)
                gsc0[wv*272 + (((lane >> 4) << 2) + qq)*17 + col16] = g0A[qq] + g0B[qq];
            asm volatile("s_waitcnt lgkmcnt(0)" ::: "memory");
            const float* g = gsc0 + wv*272 + rloc*17;
            const float ig = sigm(g[jj]), fg = sigm(g[4 + jj]);
            const float gt = tanhf(g[8 + jj]), og = sigm(g[12 + jj]);
            c0 = fg*c0 + ig*gt;
            unsigned v = f2bf(og * tanhf(c0));
            unsigned p = v | (__shfl_down(v, 1) << 16);
            ull_t all = ((ull_t)__shfl_down(p, 2) << 32) | (ull_t)p;
            if (jj == 0)
                __hip_atomic_store((ull_t*)(ring0 + (size_t)SLOT(t)*HBUF
                                            + ((wv << 4) + rloc)*HH + (blk << 2)),
                                   all, RLX, AGENT);
            asm volatile("s_waitcnt vmcnt(0)" ::: "memory");
            ARRIVE(&scnt[0], 4u*(unsigned)t + 3u, 0, t + 1);
            if (t + 1 < TT) {                       // slack: x-part for t+1
                g0A[0]=bias0; g0A[1]=bias0; g0A[2]=bias0; g0A[3]=bias0;
                g0B[0]=0.f;   g0B[1]=0.f;   g0B[2]=0.f;   g0B[3]=0.f;
                const float* xp = xs + (arow*TT + (t + 1))*INF + kgrp;
                #pragma unroll 4
                for (int kc = 0; kc < 16; ++kc) {
                    const float4 x0 = *(const float4*)(xp + (kc << 5));
                    const float4 x1 = *(const float4*)(xp + (kc << 5) + 4);
                    bf16x8 a;
                    a[0]=(short)f2bf(x0.x); a[1]=(short)f2bf(x0.y); a[2]=(short)f2bf(x0.z); a[3]=(short)f2bf(x0.w);
                    a[4]=(short)f2bf(x1.x); a[5]=(short)f2bf(x1.y); a[6]=(short)f2bf(x1.z); a[7]=(short)f2bf(x1.w);
                    const bf16x8 b = *(const bf16x8*)(w0p + ((32 + kc) << 5));
                    if (kc & 1) g0B = MFMA(a, b, g0B); else g0A = MFMA(a, b, g0A);
                }
            }
        }
    } else {
        // ---------- L1 worker: layer-1 step t-1 at loop t ----------
        const float bias1 = bih1[grl] + bhh1[grl];
        float c1 = 0.f;
        for (int t = 1; t <= TT; ++t) {
            unsigned ncc1 = 0;
            if constexpr (DEPTH <= TT) {
                if (t - 1 >= DEPTH) ncc1 = (unsigned)((t - 1 - DEPTH)/8 + 1);
            }
            // phase 1: h1(t-2) part — own-layer gate (fills L0's wait window)
            POLL3(0, t - 1, ncc1);
            f32x4 g1A = { bias1, bias1, bias1, bias1 }, g1B = { 0.f, 0.f, 0.f, 0.f };
            const u16* h1p = ring1 + (size_t)SLOT(t - 2)*HBUF + arow*HH + kgrp;
            #pragma unroll 4
            for (int kc = 0; kc < 32; ++kc) {
                const bf16x8 a = ld16<PLAIN>(h1p + (kc << 5));
                const bf16x8 b = *(const bf16x8*)(w1p + ((32 + kc) << 5));
                if (kc & 1) g1B = MFMA(a, b, g1B); else g1A = MFMA(a, b, g1A);
            }
            // phase 2: h0(t-1) part
            POLL3(t, 0, 0);
            const u16* h0p = ring0 + (size_t)SLOT(t - 1)*HBUF + arow*HH + kgrp;
            #pragma unroll 4
            for (int kc = 0; kc < 32; ++kc) {
                const bf16x8 a = ld16<PLAIN>(h0p + (kc << 5));
                const bf16x8 b = *(const bf16x8*)(w1p + (kc << 5));
                if (kc & 1) g1B = MFMA(a, b, g1B); else g1A = MFMA(a, b, g1A);
            }
            #pragma unroll
            for (int qq = 0; qq < 4; ++qq)
                gsc1[wv*272 + (((lane >> 4) << 2) + qq)*17 + col16] = g1A[qq] + g1B[qq];
            asm volatile("s_waitcnt lgkmcnt(0)" ::: "memory");
            const float* g = gsc1 + wv*272 + rloc*17;
            const float ig = sigm(g[jj]), fg = sigm(g[4 + jj]);
            const float gt = tanhf(g[8 + jj]), og = sigm(g[12 + jj]);
            c1 = fg*c1 + ig*gt;
            unsigned v = f2bf(og * tanhf(c1));
            unsigned p = v | (__shfl_down(v, 1) << 16);
            ull_t all = ((ull_t)__shfl_down(p, 2) << 32) | (ull_t)p;
            if (jj == 0)
                __hip_atomic_store((ull_t*)(ring1 + (size_t)SLOT(t - 1)*HBUF
                                            + ((wv << 4) + rloc)*HH + (blk << 2)),
                                   all, RLX, AGENT);
            asm volatile("s_waitcnt vmcnt(0)" ::: "memory");
            ARRIVE(&scnt[1], 4u*(unsigned)(t - 1) + 3u, 2048, t);
        }
    }
#undef SLOT
}

template<int DEPTH, bool PLAIN>
static void launch_tier(const float* xs, const float* Wih0, const float* Whh0,
                        const float* bih0, const float* bhh0,
                        const float* Wih1, const float* Whh1,
                        const float* bih1, const float* bhh1,
                        const float* Wcls, const float* bcls,
                        float* out, void* d_ws, hipStream_t stream) {
    u16* hws = (u16*)d_ws;
    size_t ringB = (size_t)DEPTH*HBUF*2;
    unsigned* bar = (unsigned*)((char*)d_ws + 2*ringB);
    (void)hipMemsetAsync(hws, 0, 2*(size_t)HBUF*2, stream);                 // h0(-1),h0(-2)=0
    (void)hipMemsetAsync((char*)hws + ringB, 0, 2*(size_t)HBUF*2, stream);  // h1(-1),h1(-2)=0
    (void)hipMemsetAsync(bar, 0, BAR_BYTES, stream);
    (void)hipFuncSetAttribute((const void*)lstm_persist<DEPTH, PLAIN>,
                              hipFuncAttributeMaxDynamicSharedMemorySize, SMEM_BYTES);
    lstm_persist<DEPTH, PLAIN><<<dim3(256), dim3(576), SMEM_BYTES, stream>>>(
        xs, Wih0, Whh0, bih0, bhh0, Wih1, Whh1, bih1, bhh1, Wcls, bcls,
        out, hws, bar);
}

extern "C" void kernel_launch(void* const* d_in, const int* in_sizes, int n_in,
                              void* d_out, int out_size, void* d_ws, size_t ws_size,
                              hipStream_t stream) {
    const float* xs   = (const float*)d_in[0];
    const float* Wih0 = (const float*)d_in[1];
    const float* Whh0 = (const float*)d_in[2];
    const float* bih0 = (const float*)d_in[3];
    const float* bhh0 = (const float*)d_in[4];
    const float* Wih1 = (const float*)d_in[5];
    const float* Whh1 = (const float*)d_in[6];
    const float* bih1 = (const float*)d_in[7];
    const float* bhh1 = (const float*)d_in[8];
    const float* Wcls = (const float*)d_in[9];
    const float* bcls = (const float*)d_in[10];
    float* out = (float*)d_out;

    auto need = [](int depth) { return (size_t)2*depth*HBUF*2 + BAR_BYTES; };

    if (ws_size >= need(258))       // never-reused slots: plain cached loads, no fences
        launch_tier<258, true >(xs,Wih0,Whh0,bih0,bhh0,Wih1,Whh1,bih1,bhh1,Wcls,bcls,out,d_ws,stream);
    else if (ws_size >= need(32))
        launch_tier< 32, false>(xs,Wih0,Whh0,bih0,bhh0,Wih1,Whh1,bih1,bhh1,Wcls,bcls,out,d_ws,stream);
    else if (ws_size >= need(16))
        launch_tier< 16, false>(xs,Wih0,Whh0,bih0,bhh0,Wih1,Whh1,bih1,bhh1,Wcls,bcls,out,d_ws,stream);
    else
        launch_tier<  8, false>(xs,Wih0,Whh0,bih0,bhh0,Wih1,Whh1,bih1,bhh1,Wcls,bcls,out,d_ws,stream);
}